// Round 1
// baseline (3867.228 us; speedup 1.0000x reference)
//
#include <hip/hip_runtime.h>
#include <stdint.h>
#include <stddef.h>

// ---------------- problem constants ----------------
constexpr int Bb  = 4;
constexpr int Nn  = 2048;
constexpr int Ee  = 1024;    // embed dim
constexpr int KVd = 512;     // kv dim
constexpr int HDd = 128;     // head dim
constexpr int KVH = 4;       // kv heads
constexpr int Tt  = Bb * Nn; // 8192 tokens

// ---------------- workspace layout (bytes) ----------------
constexpr size_t OFF_STATS = 0;                                  // 8 floats
constexpr size_t OFF_SQ  = 256;                                  // 1 MB  int8 sign(w_q-mean)
constexpr size_t OFF_SK  = OFF_SQ  + (size_t)Ee*Ee;              // 512 KB
constexpr size_t OFF_SV  = OFF_SK  + (size_t)KVd*Ee;             // 512 KB
constexpr size_t OFF_SO  = OFF_SV  + (size_t)KVd*Ee;             // 512 KB
constexpr size_t OFF_XQQ = OFF_SO  + (size_t)Ee*KVd;             // 8 MB  int8 quant inputs
constexpr size_t OFF_XQK = OFF_XQQ + (size_t)Tt*Ee;
constexpr size_t OFF_XQV = OFF_XQK + (size_t)Tt*Ee;
constexpr size_t OFF_XSQ = OFF_XQV + (size_t)Tt*Ee;              // per-token dequant scales
constexpr size_t OFF_XSK = OFF_XSQ + (size_t)Tt*4;
constexpr size_t OFF_XSV = OFF_XSK + (size_t)Tt*4;
constexpr size_t OFF_PQ  = OFF_XSV + (size_t)Tt*4;               // 32 MB fp32 q-proj
constexpr size_t OFF_PK  = OFF_PQ  + (size_t)Tt*Ee*4;            // 16 MB
constexpr size_t OFF_PV  = OFF_PK  + (size_t)Tt*KVd*4;           // 16 MB
// aliases (regions dead by the time these are written):
constexpr size_t OFF_AO  = OFF_XQQ;                              // 16 MB over XQQ+XQK
constexpr size_t OFF_OQ  = OFF_XQV;                              // 4 MB over XQV
constexpr size_t OFF_OS  = OFF_OQ + (size_t)Tt*KVd;              // 32 KB, still inside XQV

// ---------------- weight stats: mean and mean|.| ----------------
__global__ __launch_bounds__(256) void weight_stats(
    const float* __restrict__ w0, const float* __restrict__ w1,
    const float* __restrict__ w2, const float* __restrict__ w3,
    float* __restrict__ stats)
{
  const float* w; int n;
  switch (blockIdx.x) {
    case 0:  w = w0; n = Ee*Ee;  break;
    case 1:  w = w1; n = KVd*Ee; break;
    case 2:  w = w2; n = KVd*Ee; break;
    default: w = w3; n = Ee*KVd; break;
  }
  double s = 0.0, sa = 0.0;
  for (int i = threadIdx.x; i < n; i += 256) {
    float v = w[i];
    s  += (double)v;
    sa += (double)fabsf(v);
  }
  __shared__ double r0[256], r1[256];
  r0[threadIdx.x] = s; r1[threadIdx.x] = sa;
  __syncthreads();
  for (int st = 128; st > 0; st >>= 1) {
    if (threadIdx.x < st) { r0[threadIdx.x] += r0[threadIdx.x+st]; r1[threadIdx.x] += r1[threadIdx.x+st]; }
    __syncthreads();
  }
  if (threadIdx.x == 0) {
    stats[2*blockIdx.x]   = (float)(r0[0] / n);   // mean
    stats[2*blockIdx.x+1] = (float)(r1[0] / n);   // mean |.| = ternary scale
  }
}

// ---------------- ternary weight signs ----------------
__global__ __launch_bounds__(256) void quant_w(
    const float* __restrict__ w, int8_t* __restrict__ s, int n,
    const float* __restrict__ stats, int idx)
{
  int i = blockIdx.x * 256 + threadIdx.x;
  if (i < n) {
    float d = w[i] - stats[2*idx];
    s[i] = (d > 0.f) ? (int8_t)1 : ((d < 0.f) ? (int8_t)-1 : (int8_t)0);
  }
}

// ---------------- fused rmsnorm + int8 act quant (dim=1024) ----------------
__global__ __launch_bounds__(256) void act_quant_e(
    const float* __restrict__ x, int8_t* __restrict__ q, float* __restrict__ dq)
{
  __shared__ float r0[256], r1[256];
  __shared__ float sb[2];
  const int t = blockIdx.x, tid = threadIdx.x;
  float4 a = ((const float4*)(x + (size_t)t * Ee))[tid];
  float ss = a.x*a.x + a.y*a.y + a.z*a.z + a.w*a.w;
  float mx = fmaxf(fmaxf(fabsf(a.x), fabsf(a.y)), fmaxf(fabsf(a.z), fabsf(a.w)));
  r0[tid] = ss; r1[tid] = mx;
  __syncthreads();
  for (int st = 128; st > 0; st >>= 1) {
    if (tid < st) { r0[tid] += r0[tid+st]; r1[tid] = fmaxf(r1[tid], r1[tid+st]); }
    __syncthreads();
  }
  if (tid == 0) {
    float nrm = sqrtf(r0[0]);
    float rn  = sqrtf((float)Ee) / fmaxf(nrm, 1e-12f);
    float sc  = 127.0f / fmaxf(r1[0] * rn, 1e-5f);
    sb[0] = rn; sb[1] = sc;
    dq[t] = 1.0f / sc;
  }
  __syncthreads();
  const float rn = sb[0], sc = sb[1];
  char4 o;
  o.x = (signed char)fmaxf(fminf(rintf((a.x*rn)*sc), 127.f), -128.f);
  o.y = (signed char)fmaxf(fminf(rintf((a.y*rn)*sc), 127.f), -128.f);
  o.z = (signed char)fmaxf(fminf(rintf((a.z*rn)*sc), 127.f), -128.f);
  o.w = (signed char)fmaxf(fminf(rintf((a.w*rn)*sc), 127.f), -128.f);
  ((char4*)(q + (size_t)t * Ee))[tid] = o;
}

// ---------------- int8 x ternary GEMM, exact in fp32 ----------------
// C[m,n] = xs[m] * stats[2*widx+1] * sum_k A[m,k]*B[n,k]
__global__ __launch_bounds__(256) void gemm_i8(
    const int8_t* __restrict__ A, const int8_t* __restrict__ Bm,
    const float* __restrict__ xs, const float* __restrict__ stats, int widx,
    float* __restrict__ C, int M, int Nc, int K)
{
  __shared__ float As[64][68];   // [k][m], pad keeps 16B alignment
  __shared__ float Bs[64][68];   // [k][n]
  const int tid = threadIdx.x;
  const int tx = tid & 15, ty = tid >> 4;
  const int row0 = blockIdx.y << 6, col0 = blockIdx.x << 6;
  float acc[4][4];
  #pragma unroll
  for (int i = 0; i < 4; i++)
    #pragma unroll
    for (int j = 0; j < 4; j++) acc[i][j] = 0.f;

  const int r  = tid >> 2;
  const int c0 = (tid & 3) << 4;
  const int8_t* Aptr = A  + (size_t)(row0 + r) * K + c0;
  const int8_t* Bptr = Bm + (size_t)(col0 + r) * K + c0;

  for (int k0 = 0; k0 < K; k0 += 64) {
    int4 ra = *(const int4*)(Aptr + k0);
    int4 rb = *(const int4*)(Bptr + k0);
    const int8_t* pa = (const int8_t*)&ra;
    const int8_t* pb = (const int8_t*)&rb;
    #pragma unroll
    for (int j = 0; j < 16; j++) { As[c0+j][r] = (float)pa[j]; Bs[c0+j][r] = (float)pb[j]; }
    __syncthreads();
    #pragma unroll
    for (int kk = 0; kk < 64; kk++) {
      float4 a4 = *(const float4*)&As[kk][ty << 2];
      float4 b4 = *(const float4*)&Bs[kk][tx << 2];
      float av[4] = {a4.x, a4.y, a4.z, a4.w};
      float bv[4] = {b4.x, b4.y, b4.z, b4.w};
      #pragma unroll
      for (int i = 0; i < 4; i++)
        #pragma unroll
        for (int j = 0; j < 4; j++)
          acc[i][j] = fmaf(av[i], bv[j], acc[i][j]);
    }
    __syncthreads();
  }
  const float wsc = stats[2*widx + 1];
  #pragma unroll
  for (int i = 0; i < 4; i++) {
    int m = row0 + (ty << 2) + i;
    float rowscale = xs[m] * wsc;
    float4 ov;
    ov.x = acc[i][0]*rowscale; ov.y = acc[i][1]*rowscale;
    ov.z = acc[i][2]*rowscale; ov.w = acc[i][3]*rowscale;
    *(float4*)&C[(size_t)m * Nc + col0 + (tx << 2)] = ov;
  }
}

// ---------------- flash attention (group-summed GQA scores) ----------------
constexpr int TQ = 8;
constexpr int TS = 64;

__global__ __launch_bounds__(256) void attn_kern(
    const float* __restrict__ Pq, const float* __restrict__ Pk,
    const float* __restrict__ Pv, float* __restrict__ AO)
{
  __shared__ float qc[TQ][HDd];       // 4 KB combined queries
  __shared__ float kvf[TS * HDd];     // 32 KB, xor-swizzled float4 chunks
  __shared__ float stile[TQ][TS];     // 2 KB probabilities
  __shared__ float red[TQ][32];       // 1 KB
  __shared__ float mrow[TQ], lrow[TQ], arow[TQ];

  const int tid = threadIdx.x;
  const int qt = blockIdx.x, h = blockIdx.y, b = blockIdx.z;
  const int n0 = qt * TQ;
  const size_t tokbase = (size_t)b * Nn;

  // logits = (q_{2h} + q_{2h+1}) . k / 128   (both /sqrt(d) folds)
  for (int i = tid; i < TQ*HDd; i += 256) {
    int rr = i >> 7, d = i & (HDd - 1);
    const float* qrow = Pq + (tokbase + n0 + rr) * Ee + (2*h) * HDd;
    qc[rr][d] = (qrow[d] + qrow[HDd + d]) * (1.0f/128.0f);
  }
  if (tid < TQ) { mrow[tid] = -3.0e38f; lrow[tid] = 0.0f; }

  const int r = tid >> 5;   // 0..7 query row in tile
  const int c = tid & 31;   // 0..31
  const int c1 = c + 32;
  float ox = 0.f, oy = 0.f, oz = 0.f, ow = 0.f;

  for (int kt = 0; kt < Nn/TS; kt++) {
    __syncthreads();                              // kvf + stile free
    for (int i = tid; i < TS*(HDd/4); i += 256) { // stage K tile (swizzled)
      int srow = i >> 5, j = i & 31;
      float4 v = *(const float4*)&Pk[(tokbase + (size_t)kt*TS + srow) * KVd + h*HDd + j*4];
      *(float4*)&kvf[srow*HDd + ((j ^ srow) & 31) * 4] = v;
    }
    __syncthreads();
    float a0 = 0.f, a1 = 0.f;                     // S entries (r,c), (r,c+32)
    #pragma unroll
    for (int i = 0; i < HDd/4; i++) {
      float4 qv = *(const float4*)&qc[r][i*4];
      float4 k0 = *(const float4*)&kvf[c *HDd + ((i ^ c ) & 31) * 4];
      float4 k1 = *(const float4*)&kvf[c1*HDd + ((i ^ c1) & 31) * 4];
      a0 = fmaf(qv.x,k0.x, fmaf(qv.y,k0.y, fmaf(qv.z,k0.z, fmaf(qv.w,k0.w, a0))));
      a1 = fmaf(qv.x,k1.x, fmaf(qv.y,k1.y, fmaf(qv.z,k1.z, fmaf(qv.w,k1.w, a1))));
    }
    red[r][c] = fmaxf(a0, a1);
    __syncthreads();
    if (c == 0) {
      float tm = -3.0e38f;
      for (int j = 0; j < 32; j++) tm = fmaxf(tm, red[r][j]);
      float mold = mrow[r];
      float mnew = fmaxf(mold, tm);
      arow[r] = __expf(mold - mnew);
      mrow[r] = mnew;
    }
    __syncthreads();
    const float mnew = mrow[r];
    const float alpha = arow[r];
    float p0 = __expf(a0 - mnew);
    float p1 = __expf(a1 - mnew);
    stile[r][c]  = p0;
    stile[r][c1] = p1;
    red[r][c] = p0 + p1;
    __syncthreads();
    if (c == 0) {
      float tsum = 0.f;
      for (int j = 0; j < 32; j++) tsum += red[r][j];
      lrow[r] = lrow[r] * alpha + tsum;
    }
    ox *= alpha; oy *= alpha; oz *= alpha; ow *= alpha;
    for (int i = tid; i < TS*(HDd/4); i += 256) { // stage V tile over K
      int srow = i >> 5, j = i & 31;
      float4 v = *(const float4*)&Pv[(tokbase + (size_t)kt*TS + srow) * KVd + h*HDd + j*4];
      *(float4*)&kvf[srow*HDd + ((j ^ srow) & 31) * 4] = v;
    }
    __syncthreads();
    #pragma unroll 8
    for (int s = 0; s < TS; s++) {                // O += P @ V (thread owns r, d0=4c)
      float p = stile[r][s];
      float4 v4 = *(const float4*)&kvf[s*HDd + ((c ^ s) & 31) * 4];
      ox = fmaf(p, v4.x, ox); oy = fmaf(p, v4.y, oy);
      oz = fmaf(p, v4.z, oz); ow = fmaf(p, v4.w, ow);
    }
  }
  __syncthreads();
  const float invl = 1.0f / lrow[r];
  float4 o4 = make_float4(ox*invl, oy*invl, oz*invl, ow*invl);
  *(float4*)&AO[(tokbase + n0 + r) * KVd + h*HDd + (c << 2)] = o4;
}

// ---------------- fused LayerNorm + rmsnorm + int8 quant (dim=512) ----------------
__global__ __launch_bounds__(128) void ln_quant(
    const float* __restrict__ AO, const float* __restrict__ g, const float* __restrict__ be,
    int8_t* __restrict__ oq, float* __restrict__ dq)
{
  __shared__ float r0[128], r1[128];
  __shared__ float sb[2];
  const int t = blockIdx.x, tid = threadIdx.x;
  float4 a = ((const float4*)(AO + (size_t)t * KVd))[tid];
  float s  = a.x + a.y + a.z + a.w;
  float ss = a.x*a.x + a.y*a.y + a.z*a.z + a.w*a.w;
  r0[tid] = s; r1[tid] = ss;
  __syncthreads();
  for (int st = 64; st > 0; st >>= 1) {
    if (tid < st) { r0[tid] += r0[tid+st]; r1[tid] += r1[tid+st]; }
    __syncthreads();
  }
  if (tid == 0) {
    float mu  = r0[0] / (float)KVd;
    float var = r1[0] / (float)KVd - mu*mu;
    sb[0] = mu;
    sb[1] = 1.0f / sqrtf(var + 1e-5f);
  }
  __syncthreads();
  const float mu = sb[0], iv = sb[1];
  float4 gv = ((const float4*)g)[tid];
  float4 bv = ((const float4*)be)[tid];
  float4 y;
  y.x = (a.x - mu) * iv * gv.x + bv.x;
  y.y = (a.y - mu) * iv * gv.y + bv.y;
  y.z = (a.z - mu) * iv * gv.z + bv.z;
  y.w = (a.w - mu) * iv * gv.w + bv.w;
  float ss2 = y.x*y.x + y.y*y.y + y.z*y.z + y.w*y.w;
  float mx  = fmaxf(fmaxf(fabsf(y.x), fabsf(y.y)), fmaxf(fabsf(y.z), fabsf(y.w)));
  __syncthreads();
  r0[tid] = ss2; r1[tid] = mx;
  __syncthreads();
  for (int st = 64; st > 0; st >>= 1) {
    if (tid < st) { r0[tid] += r0[tid+st]; r1[tid] = fmaxf(r1[tid], r1[tid+st]); }
    __syncthreads();
  }
  if (tid == 0) {
    float nrm = sqrtf(r0[0]);
    float rn  = sqrtf((float)KVd) / fmaxf(nrm, 1e-12f);
    float sc  = 127.0f / fmaxf(r1[0] * rn, 1e-5f);
    sb[0] = rn; sb[1] = sc;
    dq[t] = 1.0f / sc;
  }
  __syncthreads();
  const float rn = sb[0], sc = sb[1];
  char4 o;
  o.x = (signed char)fmaxf(fminf(rintf((y.x*rn)*sc), 127.f), -128.f);
  o.y = (signed char)fmaxf(fminf(rintf((y.y*rn)*sc), 127.f), -128.f);
  o.z = (signed char)fmaxf(fminf(rintf((y.z*rn)*sc), 127.f), -128.f);
  o.w = (signed char)fmaxf(fminf(rintf((y.w*rn)*sc), 127.f), -128.f);
  ((char4*)(oq + (size_t)t * KVd))[tid] = o;
}

// ---------------- launch ----------------
extern "C" void kernel_launch(void* const* d_in, const int* in_sizes, int n_in,
                              void* d_out, int out_size, void* d_ws, size_t ws_size,
                              hipStream_t stream)
{
  (void)in_sizes; (void)n_in; (void)out_size; (void)ws_size;
  const float* query = (const float*)d_in[0];
  const float* key_  = (const float*)d_in[1];
  const float* value = (const float*)d_in[2];
  const float* w_q   = (const float*)d_in[3];
  const float* w_k   = (const float*)d_in[4];
  const float* w_v   = (const float*)d_in[5];
  const float* w_o   = (const float*)d_in[6];
  const float* ln_g  = (const float*)d_in[7];
  const float* ln_b  = (const float*)d_in[8];
  float* out = (float*)d_out;

  char* ws = (char*)d_ws;
  float*  stats = (float*) (ws + OFF_STATS);
  int8_t* s_q   = (int8_t*)(ws + OFF_SQ);
  int8_t* s_k   = (int8_t*)(ws + OFF_SK);
  int8_t* s_v   = (int8_t*)(ws + OFF_SV);
  int8_t* s_o   = (int8_t*)(ws + OFF_SO);
  int8_t* xq_q  = (int8_t*)(ws + OFF_XQQ);
  int8_t* xq_k  = (int8_t*)(ws + OFF_XQK);
  int8_t* xq_v  = (int8_t*)(ws + OFF_XQV);
  float*  xs_q  = (float*) (ws + OFF_XSQ);
  float*  xs_k  = (float*) (ws + OFF_XSK);
  float*  xs_v  = (float*) (ws + OFF_XSV);
  float*  Pq    = (float*) (ws + OFF_PQ);
  float*  Pk    = (float*) (ws + OFF_PK);
  float*  Pv    = (float*) (ws + OFF_PV);
  float*  AO    = (float*) (ws + OFF_AO);   // aliases XQQ+XQK (dead after their GEMMs)
  int8_t* oq    = (int8_t*)(ws + OFF_OQ);   // aliases XQV (dead after v GEMM)
  float*  os_   = (float*) (ws + OFF_OS);

  weight_stats<<<dim3(4), dim3(256), 0, stream>>>(w_q, w_k, w_v, w_o, stats);
  quant_w<<<dim3((Ee*Ee)/256),  dim3(256), 0, stream>>>(w_q, s_q, Ee*Ee,  stats, 0);
  quant_w<<<dim3((KVd*Ee)/256), dim3(256), 0, stream>>>(w_k, s_k, KVd*Ee, stats, 1);
  quant_w<<<dim3((KVd*Ee)/256), dim3(256), 0, stream>>>(w_v, s_v, KVd*Ee, stats, 2);
  quant_w<<<dim3((Ee*KVd)/256), dim3(256), 0, stream>>>(w_o, s_o, Ee*KVd, stats, 3);

  act_quant_e<<<dim3(Tt), dim3(256), 0, stream>>>(query, xq_q, xs_q);
  act_quant_e<<<dim3(Tt), dim3(256), 0, stream>>>(key_,  xq_k, xs_k);
  act_quant_e<<<dim3(Tt), dim3(256), 0, stream>>>(value, xq_v, xs_v);

  gemm_i8<<<dim3(Ee/64,  Tt/64), dim3(256), 0, stream>>>(xq_q, s_q, xs_q, stats, 0, Pq, Tt, Ee,  Ee);
  gemm_i8<<<dim3(KVd/64, Tt/64), dim3(256), 0, stream>>>(xq_k, s_k, xs_k, stats, 1, Pk, Tt, KVd, Ee);
  gemm_i8<<<dim3(KVd/64, Tt/64), dim3(256), 0, stream>>>(xq_v, s_v, xs_v, stats, 2, Pv, Tt, KVd, Ee);

  attn_kern<<<dim3(Nn/TQ, KVH, Bb), dim3(256), 0, stream>>>(Pq, Pk, Pv, AO);

  ln_quant<<<dim3(Tt), dim3(128), 0, stream>>>(AO, ln_g, ln_b, oq, os_);

  gemm_i8<<<dim3(Ee/64, Tt/64), dim3(256), 0, stream>>>(oq, s_o, os_, stats, 3, out, Tt, Ee, KVd);
}

// Round 2
// 1945.758 us; speedup vs baseline: 1.9875x; 1.9875x over previous
//
#include <hip/hip_runtime.h>
#include <stdint.h>
#include <stddef.h>

// ---------------- problem constants ----------------
constexpr int Bb  = 4;
constexpr int Nn  = 2048;
constexpr int Ee  = 1024;    // embed dim
constexpr int KVd = 512;     // kv dim
constexpr int HDd = 128;     // head dim
constexpr int KVH = 4;       // kv heads
constexpr int Tt  = Bb * Nn; // 8192 tokens

// ---------------- workspace layout (bytes) ----------------
constexpr size_t OFF_STATS = 0;                                  // 8 floats
constexpr size_t OFF_SQ  = 256;                                  // 1 MB  int8 sign(w_q-mean)
constexpr size_t OFF_SK  = OFF_SQ  + (size_t)Ee*Ee;              // 512 KB
constexpr size_t OFF_SV  = OFF_SK  + (size_t)KVd*Ee;             // 512 KB
constexpr size_t OFF_SO  = OFF_SV  + (size_t)KVd*Ee;             // 512 KB
constexpr size_t OFF_XQQ = OFF_SO  + (size_t)Ee*KVd;             // 8 MB  int8 quant inputs
constexpr size_t OFF_XQK = OFF_XQQ + (size_t)Tt*Ee;
constexpr size_t OFF_XQV = OFF_XQK + (size_t)Tt*Ee;
constexpr size_t OFF_XSQ = OFF_XQV + (size_t)Tt*Ee;              // per-token dequant scales
constexpr size_t OFF_XSK = OFF_XSQ + (size_t)Tt*4;
constexpr size_t OFF_XSV = OFF_XSK + (size_t)Tt*4;
constexpr size_t OFF_PQ  = OFF_XSV + (size_t)Tt*4;               // 32 MB fp32 q-proj
constexpr size_t OFF_PK  = OFF_PQ  + (size_t)Tt*Ee*4;            // 16 MB
constexpr size_t OFF_PV  = OFF_PK  + (size_t)Tt*KVd*4;           // 16 MB
// aliases (regions dead by the time these are written):
constexpr size_t OFF_AO  = OFF_XQQ;                              // 16 MB over XQQ+XQK
constexpr size_t OFF_OQ  = OFF_XQV;                              // 4 MB over XQV
constexpr size_t OFF_OS  = OFF_OQ + (size_t)Tt*KVd;              // 32 KB, still inside XQV
constexpr size_t OFF_PART = OFF_PQ;                              // 4 KB partials alias Pq
                                                                 // (consumed before Pq written)

// ---------------- weight stats, stage 1: 64 blocks x 4 matrices ----------------
// Deterministic partition (fixed grid-stride), double accumulation.
constexpr int SB = 64;  // stat blocks per matrix

__global__ __launch_bounds__(256) void weight_stats_part(
    const float* __restrict__ w0, const float* __restrict__ w1,
    const float* __restrict__ w2, const float* __restrict__ w3,
    double* __restrict__ partials)
{
  const float* w; int n;
  switch (blockIdx.y) {
    case 0:  w = w0; n = Ee*Ee;  break;
    case 1:  w = w1; n = KVd*Ee; break;
    case 2:  w = w2; n = KVd*Ee; break;
    default: w = w3; n = Ee*KVd; break;
  }
  const int nv = n >> 2;
  double s = 0.0, sa = 0.0;
  for (int i = blockIdx.x * 256 + threadIdx.x; i < nv; i += SB * 256) {
    float4 v = ((const float4*)w)[i];
    s  += (double)v.x + (double)v.y + (double)v.z + (double)v.w;
    sa += (double)fabsf(v.x) + (double)fabsf(v.y) + (double)fabsf(v.z) + (double)fabsf(v.w);
  }
  __shared__ double r0[256], r1[256];
  r0[threadIdx.x] = s; r1[threadIdx.x] = sa;
  __syncthreads();
  for (int st = 128; st > 0; st >>= 1) {
    if (threadIdx.x < st) { r0[threadIdx.x] += r0[threadIdx.x+st]; r1[threadIdx.x] += r1[threadIdx.x+st]; }
    __syncthreads();
  }
  if (threadIdx.x == 0) {
    size_t o = ((size_t)blockIdx.y * SB + blockIdx.x) * 2;
    partials[o]   = r0[0];
    partials[o+1] = r1[0];
  }
}

// ---------------- weight stats, stage 2: finalize ----------------
__global__ __launch_bounds__(64) void weight_stats_fin(
    const double* __restrict__ partials, float* __restrict__ stats)
{
  int m = threadIdx.x;
  if (m < 4) {
    double s = 0.0, sa = 0.0;
    for (int i = 0; i < SB; i++) {
      s  += partials[((size_t)m * SB + i) * 2];
      sa += partials[((size_t)m * SB + i) * 2 + 1];
    }
    int n = (m == 0) ? Ee*Ee : (m == 3 ? Ee*KVd : KVd*Ee);
    stats[2*m]   = (float)(s  / n);   // mean
    stats[2*m+1] = (float)(sa / n);   // mean |.| = ternary scale
  }
}

// ---------------- ternary weight signs ----------------
__global__ __launch_bounds__(256) void quant_w(
    const float* __restrict__ w, int8_t* __restrict__ s, int n,
    const float* __restrict__ stats, int idx)
{
  int i = blockIdx.x * 256 + threadIdx.x;
  if (i < n) {
    float d = w[i] - stats[2*idx];
    s[i] = (d > 0.f) ? (int8_t)1 : ((d < 0.f) ? (int8_t)-1 : (int8_t)0);
  }
}

// ---------------- fused rmsnorm + int8 act quant (dim=1024) ----------------
__global__ __launch_bounds__(256) void act_quant_e(
    const float* __restrict__ x, int8_t* __restrict__ q, float* __restrict__ dq)
{
  __shared__ float r0[256], r1[256];
  __shared__ float sb[2];
  const int t = blockIdx.x, tid = threadIdx.x;
  float4 a = ((const float4*)(x + (size_t)t * Ee))[tid];
  float ss = a.x*a.x + a.y*a.y + a.z*a.z + a.w*a.w;
  float mx = fmaxf(fmaxf(fabsf(a.x), fabsf(a.y)), fmaxf(fabsf(a.z), fabsf(a.w)));
  r0[tid] = ss; r1[tid] = mx;
  __syncthreads();
  for (int st = 128; st > 0; st >>= 1) {
    if (tid < st) { r0[tid] += r0[tid+st]; r1[tid] = fmaxf(r1[tid], r1[tid+st]); }
    __syncthreads();
  }
  if (tid == 0) {
    float nrm = sqrtf(r0[0]);
    float rn  = sqrtf((float)Ee) / fmaxf(nrm, 1e-12f);
    float sc  = 127.0f / fmaxf(r1[0] * rn, 1e-5f);
    sb[0] = rn; sb[1] = sc;
    dq[t] = 1.0f / sc;
  }
  __syncthreads();
  const float rn = sb[0], sc = sb[1];
  char4 o;
  o.x = (signed char)fmaxf(fminf(rintf((a.x*rn)*sc), 127.f), -128.f);
  o.y = (signed char)fmaxf(fminf(rintf((a.y*rn)*sc), 127.f), -128.f);
  o.z = (signed char)fmaxf(fminf(rintf((a.z*rn)*sc), 127.f), -128.f);
  o.w = (signed char)fmaxf(fminf(rintf((a.w*rn)*sc), 127.f), -128.f);
  ((char4*)(q + (size_t)t * Ee))[tid] = o;
}

// ---------------- int8 x ternary GEMM, exact in fp32 ----------------
// C[m,n] = xs[m] * stats[2*widx+1] * sum_k A[m,k]*B[n,k]
__global__ __launch_bounds__(256) void gemm_i8(
    const int8_t* __restrict__ A, const int8_t* __restrict__ Bm,
    const float* __restrict__ xs, const float* __restrict__ stats, int widx,
    float* __restrict__ C, int M, int Nc, int K)
{
  __shared__ float As[64][68];   // [k][m], pad keeps 16B alignment
  __shared__ float Bs[64][68];   // [k][n]
  const int tid = threadIdx.x;
  const int tx = tid & 15, ty = tid >> 4;
  const int row0 = blockIdx.y << 6, col0 = blockIdx.x << 6;
  float acc[4][4];
  #pragma unroll
  for (int i = 0; i < 4; i++)
    #pragma unroll
    for (int j = 0; j < 4; j++) acc[i][j] = 0.f;

  const int r  = tid >> 2;
  const int c0 = (tid & 3) << 4;
  const int8_t* Aptr = A  + (size_t)(row0 + r) * K + c0;
  const int8_t* Bptr = Bm + (size_t)(col0 + r) * K + c0;

  for (int k0 = 0; k0 < K; k0 += 64) {
    int4 ra = *(const int4*)(Aptr + k0);
    int4 rb = *(const int4*)(Bptr + k0);
    const int8_t* pa = (const int8_t*)&ra;
    const int8_t* pb = (const int8_t*)&rb;
    #pragma unroll
    for (int j = 0; j < 16; j++) { As[c0+j][r] = (float)pa[j]; Bs[c0+j][r] = (float)pb[j]; }
    __syncthreads();
    #pragma unroll
    for (int kk = 0; kk < 64; kk++) {
      float4 a4 = *(const float4*)&As[kk][ty << 2];
      float4 b4 = *(const float4*)&Bs[kk][tx << 2];
      float av[4] = {a4.x, a4.y, a4.z, a4.w};
      float bv[4] = {b4.x, b4.y, b4.z, b4.w};
      #pragma unroll
      for (int i = 0; i < 4; i++)
        #pragma unroll
        for (int j = 0; j < 4; j++)
          acc[i][j] = fmaf(av[i], bv[j], acc[i][j]);
    }
    __syncthreads();
  }
  const float wsc = stats[2*widx + 1];
  #pragma unroll
  for (int i = 0; i < 4; i++) {
    int m = row0 + (ty << 2) + i;
    float rowscale = xs[m] * wsc;
    float4 ov;
    ov.x = acc[i][0]*rowscale; ov.y = acc[i][1]*rowscale;
    ov.z = acc[i][2]*rowscale; ov.w = acc[i][3]*rowscale;
    *(float4*)&C[(size_t)m * Nc + col0 + (tx << 2)] = ov;
  }
}

// ---------------- flash attention (group-summed GQA scores) ----------------
constexpr int TQ = 8;
constexpr int TS = 64;

__global__ __launch_bounds__(256) void attn_kern(
    const float* __restrict__ Pq, const float* __restrict__ Pk,
    const float* __restrict__ Pv, float* __restrict__ AO)
{
  __shared__ float qc[TQ][HDd];       // 4 KB combined queries
  __shared__ float kvf[TS * HDd];     // 32 KB, xor-swizzled float4 chunks
  __shared__ float stile[TQ][TS];     // 2 KB probabilities
  __shared__ float red[TQ][32];       // 1 KB
  __shared__ float mrow[TQ], lrow[TQ], arow[TQ];

  const int tid = threadIdx.x;
  const int qt = blockIdx.x, h = blockIdx.y, b = blockIdx.z;
  const int n0 = qt * TQ;
  const size_t tokbase = (size_t)b * Nn;

  // logits = (q_{2h} + q_{2h+1}) . k / 128   (both /sqrt(d) folds)
  for (int i = tid; i < TQ*HDd; i += 256) {
    int rr = i >> 7, d = i & (HDd - 1);
    const float* qrow = Pq + (tokbase + n0 + rr) * Ee + (2*h) * HDd;
    qc[rr][d] = (qrow[d] + qrow[HDd + d]) * (1.0f/128.0f);
  }
  if (tid < TQ) { mrow[tid] = -3.0e38f; lrow[tid] = 0.0f; }

  const int r = tid >> 5;   // 0..7 query row in tile
  const int c = tid & 31;   // 0..31
  const int c1 = c + 32;
  float ox = 0.f, oy = 0.f, oz = 0.f, ow = 0.f;

  for (int kt = 0; kt < Nn/TS; kt++) {
    __syncthreads();                              // kvf + stile free
    for (int i = tid; i < TS*(HDd/4); i += 256) { // stage K tile (swizzled)
      int srow = i >> 5, j = i & 31;
      float4 v = *(const float4*)&Pk[(tokbase + (size_t)kt*TS + srow) * KVd + h*HDd + j*4];
      *(float4*)&kvf[srow*HDd + ((j ^ srow) & 31) * 4] = v;
    }
    __syncthreads();
    float a0 = 0.f, a1 = 0.f;                     // S entries (r,c), (r,c+32)
    #pragma unroll
    for (int i = 0; i < HDd/4; i++) {
      float4 qv = *(const float4*)&qc[r][i*4];
      float4 k0 = *(const float4*)&kvf[c *HDd + ((i ^ c ) & 31) * 4];
      float4 k1 = *(const float4*)&kvf[c1*HDd + ((i ^ c1) & 31) * 4];
      a0 = fmaf(qv.x,k0.x, fmaf(qv.y,k0.y, fmaf(qv.z,k0.z, fmaf(qv.w,k0.w, a0))));
      a1 = fmaf(qv.x,k1.x, fmaf(qv.y,k1.y, fmaf(qv.z,k1.z, fmaf(qv.w,k1.w, a1))));
    }
    red[r][c] = fmaxf(a0, a1);
    __syncthreads();
    if (c == 0) {
      float tm = -3.0e38f;
      for (int j = 0; j < 32; j++) tm = fmaxf(tm, red[r][j]);
      float mold = mrow[r];
      float mnew = fmaxf(mold, tm);
      arow[r] = __expf(mold - mnew);
      mrow[r] = mnew;
    }
    __syncthreads();
    const float mnew = mrow[r];
    const float alpha = arow[r];
    float p0 = __expf(a0 - mnew);
    float p1 = __expf(a1 - mnew);
    stile[r][c]  = p0;
    stile[r][c1] = p1;
    red[r][c] = p0 + p1;
    __syncthreads();
    if (c == 0) {
      float tsum = 0.f;
      for (int j = 0; j < 32; j++) tsum += red[r][j];
      lrow[r] = lrow[r] * alpha + tsum;
    }
    ox *= alpha; oy *= alpha; oz *= alpha; ow *= alpha;
    for (int i = tid; i < TS*(HDd/4); i += 256) { // stage V tile over K
      int srow = i >> 5, j = i & 31;
      float4 v = *(const float4*)&Pv[(tokbase + (size_t)kt*TS + srow) * KVd + h*HDd + j*4];
      *(float4*)&kvf[srow*HDd + ((j ^ srow) & 31) * 4] = v;
    }
    __syncthreads();
    #pragma unroll 8
    for (int s = 0; s < TS; s++) {                // O += P @ V (thread owns r, d0=4c)
      float p = stile[r][s];
      float4 v4 = *(const float4*)&kvf[s*HDd + ((c ^ s) & 31) * 4];
      ox = fmaf(p, v4.x, ox); oy = fmaf(p, v4.y, oy);
      oz = fmaf(p, v4.z, oz); ow = fmaf(p, v4.w, ow);
    }
  }
  __syncthreads();
  const float invl = 1.0f / lrow[r];
  float4 o4 = make_float4(ox*invl, oy*invl, oz*invl, ow*invl);
  *(float4*)&AO[(tokbase + n0 + r) * KVd + h*HDd + (c << 2)] = o4;
}

// ---------------- fused LayerNorm + rmsnorm + int8 quant (dim=512) ----------------
__global__ __launch_bounds__(128) void ln_quant(
    const float* __restrict__ AO, const float* __restrict__ g, const float* __restrict__ be,
    int8_t* __restrict__ oq, float* __restrict__ dq)
{
  __shared__ float r0[128], r1[128];
  __shared__ float sb[2];
  const int t = blockIdx.x, tid = threadIdx.x;
  float4 a = ((const float4*)(AO + (size_t)t * KVd))[tid];
  float s  = a.x + a.y + a.z + a.w;
  float ss = a.x*a.x + a.y*a.y + a.z*a.z + a.w*a.w;
  r0[tid] = s; r1[tid] = ss;
  __syncthreads();
  for (int st = 64; st > 0; st >>= 1) {
    if (tid < st) { r0[tid] += r0[tid+st]; r1[tid] += r1[tid+st]; }
    __syncthreads();
  }
  if (tid == 0) {
    float mu  = r0[0] / (float)KVd;
    float var = r1[0] / (float)KVd - mu*mu;
    sb[0] = mu;
    sb[1] = 1.0f / sqrtf(var + 1e-5f);
  }
  __syncthreads();
  const float mu = sb[0], iv = sb[1];
  float4 gv = ((const float4*)g)[tid];
  float4 bv = ((const float4*)be)[tid];
  float4 y;
  y.x = (a.x - mu) * iv * gv.x + bv.x;
  y.y = (a.y - mu) * iv * gv.y + bv.y;
  y.z = (a.z - mu) * iv * gv.z + bv.z;
  y.w = (a.w - mu) * iv * gv.w + bv.w;
  float ss2 = y.x*y.x + y.y*y.y + y.z*y.z + y.w*y.w;
  float mx  = fmaxf(fmaxf(fabsf(y.x), fabsf(y.y)), fmaxf(fabsf(y.z), fabsf(y.w)));
  __syncthreads();
  r0[tid] = ss2; r1[tid] = mx;
  __syncthreads();
  for (int st = 64; st > 0; st >>= 1) {
    if (tid < st) { r0[tid] += r0[tid+st]; r1[tid] = fmaxf(r1[tid], r1[tid+st]); }
    __syncthreads();
  }
  if (tid == 0) {
    float nrm = sqrtf(r0[0]);
    float rn  = sqrtf((float)KVd) / fmaxf(nrm, 1e-12f);
    float sc  = 127.0f / fmaxf(r1[0] * rn, 1e-5f);
    sb[0] = rn; sb[1] = sc;
    dq[t] = 1.0f / sc;
  }
  __syncthreads();
  const float rn = sb[0], sc = sb[1];
  char4 o;
  o.x = (signed char)fmaxf(fminf(rintf((y.x*rn)*sc), 127.f), -128.f);
  o.y = (signed char)fmaxf(fminf(rintf((y.y*rn)*sc), 127.f), -128.f);
  o.z = (signed char)fmaxf(fminf(rintf((y.z*rn)*sc), 127.f), -128.f);
  o.w = (signed char)fmaxf(fminf(rintf((y.w*rn)*sc), 127.f), -128.f);
  ((char4*)(oq + (size_t)t * KVd))[tid] = o;
}

// ---------------- launch ----------------
extern "C" void kernel_launch(void* const* d_in, const int* in_sizes, int n_in,
                              void* d_out, int out_size, void* d_ws, size_t ws_size,
                              hipStream_t stream)
{
  (void)in_sizes; (void)n_in; (void)out_size; (void)ws_size;
  const float* query = (const float*)d_in[0];
  const float* key_  = (const float*)d_in[1];
  const float* value = (const float*)d_in[2];
  const float* w_q   = (const float*)d_in[3];
  const float* w_k   = (const float*)d_in[4];
  const float* w_v   = (const float*)d_in[5];
  const float* w_o   = (const float*)d_in[6];
  const float* ln_g  = (const float*)d_in[7];
  const float* ln_b  = (const float*)d_in[8];
  float* out = (float*)d_out;

  char* ws = (char*)d_ws;
  float*  stats = (float*) (ws + OFF_STATS);
  int8_t* s_q   = (int8_t*)(ws + OFF_SQ);
  int8_t* s_k   = (int8_t*)(ws + OFF_SK);
  int8_t* s_v   = (int8_t*)(ws + OFF_SV);
  int8_t* s_o   = (int8_t*)(ws + OFF_SO);
  int8_t* xq_q  = (int8_t*)(ws + OFF_XQQ);
  int8_t* xq_k  = (int8_t*)(ws + OFF_XQK);
  int8_t* xq_v  = (int8_t*)(ws + OFF_XQV);
  float*  xs_q  = (float*) (ws + OFF_XSQ);
  float*  xs_k  = (float*) (ws + OFF_XSK);
  float*  xs_v  = (float*) (ws + OFF_XSV);
  float*  Pq    = (float*) (ws + OFF_PQ);
  float*  Pk    = (float*) (ws + OFF_PK);
  float*  Pv    = (float*) (ws + OFF_PV);
  double* part  = (double*)(ws + OFF_PART);  // aliases Pq (consumed before Pq written)
  float*  AO    = (float*) (ws + OFF_AO);    // aliases XQQ+XQK (dead after their GEMMs)
  int8_t* oq    = (int8_t*)(ws + OFF_OQ);    // aliases XQV (dead after v GEMM)
  float*  os_   = (float*) (ws + OFF_OS);

  weight_stats_part<<<dim3(SB, 4), dim3(256), 0, stream>>>(w_q, w_k, w_v, w_o, part);
  weight_stats_fin<<<dim3(1), dim3(64), 0, stream>>>(part, stats);

  quant_w<<<dim3((Ee*Ee)/256),  dim3(256), 0, stream>>>(w_q, s_q, Ee*Ee,  stats, 0);
  quant_w<<<dim3((KVd*Ee)/256), dim3(256), 0, stream>>>(w_k, s_k, KVd*Ee, stats, 1);
  quant_w<<<dim3((KVd*Ee)/256), dim3(256), 0, stream>>>(w_v, s_v, KVd*Ee, stats, 2);
  quant_w<<<dim3((Ee*KVd)/256), dim3(256), 0, stream>>>(w_o, s_o, Ee*KVd, stats, 3);

  act_quant_e<<<dim3(Tt), dim3(256), 0, stream>>>(query, xq_q, xs_q);
  act_quant_e<<<dim3(Tt), dim3(256), 0, stream>>>(key_,  xq_k, xs_k);
  act_quant_e<<<dim3(Tt), dim3(256), 0, stream>>>(value, xq_v, xs_v);

  gemm_i8<<<dim3(Ee/64,  Tt/64), dim3(256), 0, stream>>>(xq_q, s_q, xs_q, stats, 0, Pq, Tt, Ee,  Ee);
  gemm_i8<<<dim3(KVd/64, Tt/64), dim3(256), 0, stream>>>(xq_k, s_k, xs_k, stats, 1, Pk, Tt, KVd, Ee);
  gemm_i8<<<dim3(KVd/64, Tt/64), dim3(256), 0, stream>>>(xq_v, s_v, xs_v, stats, 2, Pv, Tt, KVd, Ee);

  attn_kern<<<dim3(Nn/TQ, KVH, Bb), dim3(256), 0, stream>>>(Pq, Pk, Pv, AO);

  ln_quant<<<dim3(Tt), dim3(128), 0, stream>>>(AO, ln_g, ln_b, oq, os_);

  gemm_i8<<<dim3(Ee/64, Tt/64), dim3(256), 0, stream>>>(oq, s_o, os_, stats, 3, out, Tt, Ee, KVd);
}

// Round 3
// 1006.218 us; speedup vs baseline: 3.8433x; 1.9337x over previous
//
#include <hip/hip_runtime.h>
#include <stdint.h>
#include <stddef.h>

// ---------------- problem constants ----------------
constexpr int Bb  = 4;
constexpr int Nn  = 2048;
constexpr int Ee  = 1024;    // embed dim
constexpr int KVd = 512;     // kv dim
constexpr int HDd = 128;     // head dim
constexpr int KVH = 4;       // kv heads
constexpr int Tt  = Bb * Nn; // 8192 tokens

typedef _Float16 half8 __attribute__((ext_vector_type(8)));
typedef float    float4_t __attribute__((ext_vector_type(4)));

// ---------------- workspace layout (bytes) ----------------
constexpr size_t OFF_STATS = 0;                                  // 8 floats
constexpr size_t OFF_SQ  = 256;                                  // 1 MB  int8 sign(w_q-mean)
constexpr size_t OFF_SK  = OFF_SQ  + (size_t)Ee*Ee;              // 512 KB
constexpr size_t OFF_SV  = OFF_SK  + (size_t)KVd*Ee;             // 512 KB
constexpr size_t OFF_SO  = OFF_SV  + (size_t)KVd*Ee;             // 512 KB
constexpr size_t OFF_XQQ = OFF_SO  + (size_t)Ee*KVd;             // 8 MB  int8 quant inputs
constexpr size_t OFF_XQK = OFF_XQQ + (size_t)Tt*Ee;
constexpr size_t OFF_XQV = OFF_XQK + (size_t)Tt*Ee;
constexpr size_t OFF_XSQ = OFF_XQV + (size_t)Tt*Ee;              // per-token dequant scales
constexpr size_t OFF_XSK = OFF_XSQ + (size_t)Tt*4;
constexpr size_t OFF_XSV = OFF_XSK + (size_t)Tt*4;
constexpr size_t OFF_PQ  = OFF_XSV + (size_t)Tt*4;               // 32 MB fp32 q-proj
constexpr size_t OFF_PK  = OFF_PQ  + (size_t)Tt*Ee*4;            // 16 MB
constexpr size_t OFF_PV  = OFF_PK  + (size_t)Tt*KVd*4;           // 16 MB
// aliases (regions dead by the time these are written):
constexpr size_t OFF_PKH = OFF_XQQ;                              // 8 MB f16 K (xq_q dead after gemm Q)
constexpr size_t OFF_PVT = OFF_XQK;                              // 8 MB f16 V^T (xq_k dead after gemm K)
constexpr size_t OFF_AO  = OFF_PK;                               // 16 MB over Pk fp32 (dead after k_to_f16)
constexpr size_t OFF_OQ  = OFF_XQV;                              // 4 MB over XQV (dead after gemm V)
constexpr size_t OFF_OS  = OFF_OQ + (size_t)Tt*KVd;              // 32 KB, still inside XQV
constexpr size_t OFF_PART = OFF_PQ;                              // 4 KB partials alias Pq (consumed first)

// ---------------- weight stats, stage 1 ----------------
constexpr int SB = 64;  // stat blocks per matrix

__global__ __launch_bounds__(256) void weight_stats_part(
    const float* __restrict__ w0, const float* __restrict__ w1,
    const float* __restrict__ w2, const float* __restrict__ w3,
    double* __restrict__ partials)
{
  const float* w; int n;
  switch (blockIdx.y) {
    case 0:  w = w0; n = Ee*Ee;  break;
    case 1:  w = w1; n = KVd*Ee; break;
    case 2:  w = w2; n = KVd*Ee; break;
    default: w = w3; n = Ee*KVd; break;
  }
  const int nv = n >> 2;
  double s = 0.0, sa = 0.0;
  for (int i = blockIdx.x * 256 + threadIdx.x; i < nv; i += SB * 256) {
    float4 v = ((const float4*)w)[i];
    s  += (double)v.x + (double)v.y + (double)v.z + (double)v.w;
    sa += (double)fabsf(v.x) + (double)fabsf(v.y) + (double)fabsf(v.z) + (double)fabsf(v.w);
  }
  __shared__ double r0[256], r1[256];
  r0[threadIdx.x] = s; r1[threadIdx.x] = sa;
  __syncthreads();
  for (int st = 128; st > 0; st >>= 1) {
    if (threadIdx.x < st) { r0[threadIdx.x] += r0[threadIdx.x+st]; r1[threadIdx.x] += r1[threadIdx.x+st]; }
    __syncthreads();
  }
  if (threadIdx.x == 0) {
    size_t o = ((size_t)blockIdx.y * SB + blockIdx.x) * 2;
    partials[o]   = r0[0];
    partials[o+1] = r1[0];
  }
}

__global__ __launch_bounds__(64) void weight_stats_fin(
    const double* __restrict__ partials, float* __restrict__ stats)
{
  int m = threadIdx.x;
  if (m < 4) {
    double s = 0.0, sa = 0.0;
    for (int i = 0; i < SB; i++) {
      s  += partials[((size_t)m * SB + i) * 2];
      sa += partials[((size_t)m * SB + i) * 2 + 1];
    }
    int n = (m == 0) ? Ee*Ee : (m == 3 ? Ee*KVd : KVd*Ee);
    stats[2*m]   = (float)(s  / n);
    stats[2*m+1] = (float)(sa / n);
  }
}

// ---------------- ternary weight signs ----------------
__global__ __launch_bounds__(256) void quant_w(
    const float* __restrict__ w, int8_t* __restrict__ s, int n,
    const float* __restrict__ stats, int idx)
{
  int i = blockIdx.x * 256 + threadIdx.x;
  if (i < n) {
    float d = w[i] - stats[2*idx];
    s[i] = (d > 0.f) ? (int8_t)1 : ((d < 0.f) ? (int8_t)-1 : (int8_t)0);
  }
}

// ---------------- fused rmsnorm + int8 act quant (dim=1024) ----------------
__global__ __launch_bounds__(256) void act_quant_e(
    const float* __restrict__ x, int8_t* __restrict__ q, float* __restrict__ dq)
{
  __shared__ float r0[256], r1[256];
  __shared__ float sb[2];
  const int t = blockIdx.x, tid = threadIdx.x;
  float4 a = ((const float4*)(x + (size_t)t * Ee))[tid];
  float ss = a.x*a.x + a.y*a.y + a.z*a.z + a.w*a.w;
  float mx = fmaxf(fmaxf(fabsf(a.x), fabsf(a.y)), fmaxf(fabsf(a.z), fabsf(a.w)));
  r0[tid] = ss; r1[tid] = mx;
  __syncthreads();
  for (int st = 128; st > 0; st >>= 1) {
    if (tid < st) { r0[tid] += r0[tid+st]; r1[tid] = fmaxf(r1[tid], r1[tid+st]); }
    __syncthreads();
  }
  if (tid == 0) {
    float nrm = sqrtf(r0[0]);
    float rn  = sqrtf((float)Ee) / fmaxf(nrm, 1e-12f);
    float sc  = 127.0f / fmaxf(r1[0] * rn, 1e-5f);
    sb[0] = rn; sb[1] = sc;
    dq[t] = 1.0f / sc;
  }
  __syncthreads();
  const float rn = sb[0], sc = sb[1];
  char4 o;
  o.x = (signed char)fmaxf(fminf(rintf((a.x*rn)*sc), 127.f), -128.f);
  o.y = (signed char)fmaxf(fminf(rintf((a.y*rn)*sc), 127.f), -128.f);
  o.z = (signed char)fmaxf(fminf(rintf((a.z*rn)*sc), 127.f), -128.f);
  o.w = (signed char)fmaxf(fminf(rintf((a.w*rn)*sc), 127.f), -128.f);
  ((char4*)(q + (size_t)t * Ee))[tid] = o;
}

// ---------------- int8 x ternary GEMM, exact in fp32 ----------------
__global__ __launch_bounds__(256) void gemm_i8(
    const int8_t* __restrict__ A, const int8_t* __restrict__ Bm,
    const float* __restrict__ xs, const float* __restrict__ stats, int widx,
    float* __restrict__ C, int M, int Nc, int K)
{
  __shared__ float As[64][68];
  __shared__ float Bs[64][68];
  const int tid = threadIdx.x;
  const int tx = tid & 15, ty = tid >> 4;
  const int row0 = blockIdx.y << 6, col0 = blockIdx.x << 6;
  float acc[4][4];
  #pragma unroll
  for (int i = 0; i < 4; i++)
    #pragma unroll
    for (int j = 0; j < 4; j++) acc[i][j] = 0.f;

  const int r  = tid >> 2;
  const int c0 = (tid & 3) << 4;
  const int8_t* Aptr = A  + (size_t)(row0 + r) * K + c0;
  const int8_t* Bptr = Bm + (size_t)(col0 + r) * K + c0;

  for (int k0 = 0; k0 < K; k0 += 64) {
    int4 ra = *(const int4*)(Aptr + k0);
    int4 rb = *(const int4*)(Bptr + k0);
    const int8_t* pa = (const int8_t*)&ra;
    const int8_t* pb = (const int8_t*)&rb;
    #pragma unroll
    for (int j = 0; j < 16; j++) { As[c0+j][r] = (float)pa[j]; Bs[c0+j][r] = (float)pb[j]; }
    __syncthreads();
    #pragma unroll
    for (int kk = 0; kk < 64; kk++) {
      float4 a4 = *(const float4*)&As[kk][ty << 2];
      float4 b4 = *(const float4*)&Bs[kk][tx << 2];
      float av[4] = {a4.x, a4.y, a4.z, a4.w};
      float bv[4] = {b4.x, b4.y, b4.z, b4.w};
      #pragma unroll
      for (int i = 0; i < 4; i++)
        #pragma unroll
        for (int j = 0; j < 4; j++)
          acc[i][j] = fmaf(av[i], bv[j], acc[i][j]);
    }
    __syncthreads();
  }
  const float wsc = stats[2*widx + 1];
  #pragma unroll
  for (int i = 0; i < 4; i++) {
    int m = row0 + (ty << 2) + i;
    float rowscale = xs[m] * wsc;
    float4 ov;
    ov.x = acc[i][0]*rowscale; ov.y = acc[i][1]*rowscale;
    ov.z = acc[i][2]*rowscale; ov.w = acc[i][3]*rowscale;
    *(float4*)&C[(size_t)m * Nc + col0 + (tx << 2)] = ov;
  }
}

// ---------------- Pk fp32 -> f16 ----------------
__global__ __launch_bounds__(256) void k_to_f16(
    const float* __restrict__ pk, _Float16* __restrict__ pkh)
{
  size_t i = ((size_t)blockIdx.x * 256 + threadIdx.x) * 8;
  float4 a = *(const float4*)(pk + i);
  float4 b = *(const float4*)(pk + i + 4);
  half8 o;
  o[0]=(_Float16)a.x; o[1]=(_Float16)a.y; o[2]=(_Float16)a.z; o[3]=(_Float16)a.w;
  o[4]=(_Float16)b.x; o[5]=(_Float16)b.y; o[6]=(_Float16)b.z; o[7]=(_Float16)b.w;
  *(half8*)(pkh + i) = o;
}

// ---------------- Pv fp32 [tok][512] -> Pvt f16 [bh][d=128][s=2048] ----------------
__global__ __launch_bounds__(256) void v_transpose(
    const float* __restrict__ pv, _Float16* __restrict__ pvt)
{
  __shared__ _Float16 lt[128][72];   // stride 144 B keeps 16-B alignment
  const int st = blockIdx.x;          // s-tile (64 tokens)
  const int bh = blockIdx.y;          // b*4+h
  const int b = bh >> 2, h = bh & 3;
  const int t = threadIdx.x;
  const int dc = (t & 31) * 4, srow = t >> 5;
  #pragma unroll
  for (int p = 0; p < 8; p++) {
    int s = srow + 8 * p;
    float4 v = *(const float4*)(pv + (size_t)(b * Nn + st * 64 + s) * KVd + h * HDd + dc);
    lt[dc+0][s] = (_Float16)v.x; lt[dc+1][s] = (_Float16)v.y;
    lt[dc+2][s] = (_Float16)v.z; lt[dc+3][s] = (_Float16)v.w;
  }
  __syncthreads();
  const int d = t >> 1, sh = (t & 1) * 32;
  _Float16* op = pvt + ((size_t)bh * HDd + d) * Nn + st * 64 + sh;
  #pragma unroll
  for (int m = 0; m < 4; m++)
    *(half8*)(op + m * 8) = *(const half8*)&lt[d][sh + m * 8];
}

// ---------------- MFMA flash attention ----------------
// Per block: 1 wave, 16 q rows. logits = (q_{2h}+q_{2h+1}).k / 128.
// QK: A=Q[m=lane&15][k], B=K[n=lane&15][k].  PV: A=P (via LDS round-trip), B=V^T.
__global__ __launch_bounds__(64) void attn_mfma(
    const float* __restrict__ Pq, const _Float16* __restrict__ Pkh,
    const _Float16* __restrict__ Pvt, float* __restrict__ AO)
{
  __shared__ _Float16 stile[16 * 72];   // wave-private P tile, stride 144 B
  const int lane = threadIdx.x;
  const int c = lane & 15, quad = lane >> 4;
  const int qrow0 = blockIdx.x << 4;
  const int h = blockIdx.y, b = blockIdx.z;
  const int bh = b * KVH + h;
  const size_t tokbase = (size_t)b * Nn;

  // Q fragments in registers (combined group-sum, /128 folded)
  half8 qa[4];
  {
    const float* qp = Pq + (tokbase + qrow0 + c) * Ee + (2 * h) * HDd;
    #pragma unroll
    for (int kc = 0; kc < 4; kc++) {
      int k0 = kc * 32 + quad * 8;
      float4 u0 = *(const float4*)(qp + k0);
      float4 u1 = *(const float4*)(qp + k0 + 4);
      float4 w0 = *(const float4*)(qp + HDd + k0);
      float4 w1 = *(const float4*)(qp + HDd + k0 + 4);
      half8 q8;
      q8[0] = (_Float16)((u0.x + w0.x) * 0.0078125f);
      q8[1] = (_Float16)((u0.y + w0.y) * 0.0078125f);
      q8[2] = (_Float16)((u0.z + w0.z) * 0.0078125f);
      q8[3] = (_Float16)((u0.w + w0.w) * 0.0078125f);
      q8[4] = (_Float16)((u1.x + w1.x) * 0.0078125f);
      q8[5] = (_Float16)((u1.y + w1.y) * 0.0078125f);
      q8[6] = (_Float16)((u1.z + w1.z) * 0.0078125f);
      q8[7] = (_Float16)((u1.w + w1.w) * 0.0078125f);
      qa[kc] = q8;
    }
  }

  float4_t oa[8];
  #pragma unroll
  for (int g = 0; g < 8; g++) oa[g] = (float4_t){0.f, 0.f, 0.f, 0.f};
  float m_i[4] = {-1e30f, -1e30f, -1e30f, -1e30f};
  float l_i[4] = {0.f, 0.f, 0.f, 0.f};

  const _Float16* kbase = Pkh + tokbase * KVd + h * HDd;
  const _Float16* vbase = Pvt + (size_t)bh * HDd * Nn;

  for (int kt = 0; kt < Nn / 64; kt++) {
    const int s0 = kt * 64;
    // ---- S = Q K^T (16 x 64) ----
    float4_t sfr[4];
    #pragma unroll
    for (int nb = 0; nb < 4; nb++) {
      float4_t acc = (float4_t){0.f, 0.f, 0.f, 0.f};
      #pragma unroll
      for (int kc = 0; kc < 4; kc++) {
        half8 kb = *(const half8*)(kbase + (size_t)(s0 + nb * 16 + c) * KVd + kc * 32 + quad * 8);
        acc = __builtin_amdgcn_mfma_f32_16x16x32_f16(qa[kc], kb, acc, 0, 0, 0);
      }
      sfr[nb] = acc;
    }
    // ---- online softmax (rows quad*4+j, replicated across 16-lane group) ----
    float alpha[4];
    #pragma unroll
    for (int j = 0; j < 4; j++) {
      float t = fmaxf(fmaxf(sfr[0][j], sfr[1][j]), fmaxf(sfr[2][j], sfr[3][j]));
      t = fmaxf(t, __shfl_xor(t, 1));
      t = fmaxf(t, __shfl_xor(t, 2));
      t = fmaxf(t, __shfl_xor(t, 4));
      t = fmaxf(t, __shfl_xor(t, 8));
      float mnew = fmaxf(m_i[j], t);
      alpha[j] = __expf(m_i[j] - mnew);
      m_i[j] = mnew;
    }
    float p[4][4], rs[4];
    #pragma unroll
    for (int j = 0; j < 4; j++) rs[j] = 0.f;
    #pragma unroll
    for (int nb = 0; nb < 4; nb++)
      #pragma unroll
      for (int j = 0; j < 4; j++) {
        p[nb][j] = __expf(sfr[nb][j] - m_i[j]);
        rs[j] += p[nb][j];
      }
    #pragma unroll
    for (int j = 0; j < 4; j++) {
      float t = rs[j];
      t += __shfl_xor(t, 1);
      t += __shfl_xor(t, 2);
      t += __shfl_xor(t, 4);
      t += __shfl_xor(t, 8);
      l_i[j] = l_i[j] * alpha[j] + t;
    }
    #pragma unroll
    for (int g = 0; g < 8; g++) {
      oa[g][0] *= alpha[0]; oa[g][1] *= alpha[1];
      oa[g][2] *= alpha[2]; oa[g][3] *= alpha[3];
    }
    // ---- P: C/D layout -> LDS -> A-operand layout (m120 pattern) ----
    __syncthreads();  // WAR vs previous iteration's reads (single wave: waitcnt)
    #pragma unroll
    for (int nb = 0; nb < 4; nb++)
      #pragma unroll
      for (int j = 0; j < 4; j++)
        stile[(quad * 4 + j) * 72 + nb * 16 + c] = (_Float16)p[nb][j];
    __syncthreads();
    half8 pa0 = *(const half8*)&stile[c * 72 + quad * 8];
    half8 pa1 = *(const half8*)&stile[c * 72 + 32 + quad * 8];
    // ---- O += P V ----
    #pragma unroll
    for (int g = 0; g < 8; g++) {
      const _Float16* vp = vbase + (size_t)(g * 16 + c) * Nn + s0;
      half8 vb0 = *(const half8*)(vp + quad * 8);
      half8 vb1 = *(const half8*)(vp + 32 + quad * 8);
      oa[g] = __builtin_amdgcn_mfma_f32_16x16x32_f16(pa0, vb0, oa[g], 0, 0, 0);
      oa[g] = __builtin_amdgcn_mfma_f32_16x16x32_f16(pa1, vb1, oa[g], 0, 0, 0);
    }
  }
  // ---- epilogue ----
  float invl[4];
  #pragma unroll
  for (int j = 0; j < 4; j++) invl[j] = 1.0f / l_i[j];
  #pragma unroll
  for (int g = 0; g < 8; g++)
    #pragma unroll
    for (int j = 0; j < 4; j++)
      AO[(tokbase + qrow0 + quad * 4 + j) * KVd + h * HDd + g * 16 + c] = oa[g][j] * invl[j];
}

// ---------------- fused LayerNorm + rmsnorm + int8 quant (dim=512) ----------------
__global__ __launch_bounds__(128) void ln_quant(
    const float* __restrict__ AO, const float* __restrict__ g, const float* __restrict__ be,
    int8_t* __restrict__ oq, float* __restrict__ dq)
{
  __shared__ float r0[128], r1[128];
  __shared__ float sb[2];
  const int t = blockIdx.x, tid = threadIdx.x;
  float4 a = ((const float4*)(AO + (size_t)t * KVd))[tid];
  float s  = a.x + a.y + a.z + a.w;
  float ss = a.x*a.x + a.y*a.y + a.z*a.z + a.w*a.w;
  r0[tid] = s; r1[tid] = ss;
  __syncthreads();
  for (int st = 64; st > 0; st >>= 1) {
    if (tid < st) { r0[tid] += r0[tid+st]; r1[tid] += r1[tid+st]; }
    __syncthreads();
  }
  if (tid == 0) {
    float mu  = r0[0] / (float)KVd;
    float var = r1[0] / (float)KVd - mu*mu;
    sb[0] = mu;
    sb[1] = 1.0f / sqrtf(var + 1e-5f);
  }
  __syncthreads();
  const float mu = sb[0], iv = sb[1];
  float4 gv = ((const float4*)g)[tid];
  float4 bv = ((const float4*)be)[tid];
  float4 y;
  y.x = (a.x - mu) * iv * gv.x + bv.x;
  y.y = (a.y - mu) * iv * gv.y + bv.y;
  y.z = (a.z - mu) * iv * gv.z + bv.z;
  y.w = (a.w - mu) * iv * gv.w + bv.w;
  float ss2 = y.x*y.x + y.y*y.y + y.z*y.z + y.w*y.w;
  float mx  = fmaxf(fmaxf(fabsf(y.x), fabsf(y.y)), fmaxf(fabsf(y.z), fabsf(y.w)));
  __syncthreads();
  r0[tid] = ss2; r1[tid] = mx;
  __syncthreads();
  for (int st = 64; st > 0; st >>= 1) {
    if (tid < st) { r0[tid] += r0[tid+st]; r1[tid] = fmaxf(r1[tid], r1[tid+st]); }
    __syncthreads();
  }
  if (tid == 0) {
    float nrm = sqrtf(r0[0]);
    float rn  = sqrtf((float)KVd) / fmaxf(nrm, 1e-12f);
    float sc  = 127.0f / fmaxf(r1[0] * rn, 1e-5f);
    sb[0] = rn; sb[1] = sc;
    dq[t] = 1.0f / sc;
  }
  __syncthreads();
  const float rn = sb[0], sc = sb[1];
  char4 o;
  o.x = (signed char)fmaxf(fminf(rintf((y.x*rn)*sc), 127.f), -128.f);
  o.y = (signed char)fmaxf(fminf(rintf((y.y*rn)*sc), 127.f), -128.f);
  o.z = (signed char)fmaxf(fminf(rintf((y.z*rn)*sc), 127.f), -128.f);
  o.w = (signed char)fmaxf(fminf(rintf((y.w*rn)*sc), 127.f), -128.f);
  ((char4*)(oq + (size_t)t * KVd))[tid] = o;
}

// ---------------- launch ----------------
extern "C" void kernel_launch(void* const* d_in, const int* in_sizes, int n_in,
                              void* d_out, int out_size, void* d_ws, size_t ws_size,
                              hipStream_t stream)
{
  (void)in_sizes; (void)n_in; (void)out_size; (void)ws_size;
  const float* query = (const float*)d_in[0];
  const float* key_  = (const float*)d_in[1];
  const float* value = (const float*)d_in[2];
  const float* w_q   = (const float*)d_in[3];
  const float* w_k   = (const float*)d_in[4];
  const float* w_v   = (const float*)d_in[5];
  const float* w_o   = (const float*)d_in[6];
  const float* ln_g  = (const float*)d_in[7];
  const float* ln_b  = (const float*)d_in[8];
  float* out = (float*)d_out;

  char* ws = (char*)d_ws;
  float*     stats = (float*)    (ws + OFF_STATS);
  int8_t*    s_q   = (int8_t*)   (ws + OFF_SQ);
  int8_t*    s_k   = (int8_t*)   (ws + OFF_SK);
  int8_t*    s_v   = (int8_t*)   (ws + OFF_SV);
  int8_t*    s_o   = (int8_t*)   (ws + OFF_SO);
  int8_t*    xq_q  = (int8_t*)   (ws + OFF_XQQ);
  int8_t*    xq_k  = (int8_t*)   (ws + OFF_XQK);
  int8_t*    xq_v  = (int8_t*)   (ws + OFF_XQV);
  float*     xs_q  = (float*)    (ws + OFF_XSQ);
  float*     xs_k  = (float*)    (ws + OFF_XSK);
  float*     xs_v  = (float*)    (ws + OFF_XSV);
  float*     Pq    = (float*)    (ws + OFF_PQ);
  float*     Pk    = (float*)    (ws + OFF_PK);
  float*     Pv    = (float*)    (ws + OFF_PV);
  double*    part  = (double*)   (ws + OFF_PART); // aliases Pq (consumed before Pq written)
  _Float16*  Pkh   = (_Float16*) (ws + OFF_PKH);  // aliases xq_q (dead after gemm Q)
  _Float16*  Pvt   = (_Float16*) (ws + OFF_PVT);  // aliases xq_k (dead after gemm K)
  float*     AO    = (float*)    (ws + OFF_AO);   // aliases Pk fp32 (dead after k_to_f16)
  int8_t*    oq    = (int8_t*)   (ws + OFF_OQ);   // aliases xq_v (dead after gemm V)
  float*     os_   = (float*)    (ws + OFF_OS);

  weight_stats_part<<<dim3(SB, 4), dim3(256), 0, stream>>>(w_q, w_k, w_v, w_o, part);
  weight_stats_fin<<<dim3(1), dim3(64), 0, stream>>>(part, stats);

  quant_w<<<dim3((Ee*Ee)/256),  dim3(256), 0, stream>>>(w_q, s_q, Ee*Ee,  stats, 0);
  quant_w<<<dim3((KVd*Ee)/256), dim3(256), 0, stream>>>(w_k, s_k, KVd*Ee, stats, 1);
  quant_w<<<dim3((KVd*Ee)/256), dim3(256), 0, stream>>>(w_v, s_v, KVd*Ee, stats, 2);
  quant_w<<<dim3((Ee*KVd)/256), dim3(256), 0, stream>>>(w_o, s_o, Ee*KVd, stats, 3);

  act_quant_e<<<dim3(Tt), dim3(256), 0, stream>>>(query, xq_q, xs_q);
  act_quant_e<<<dim3(Tt), dim3(256), 0, stream>>>(key_,  xq_k, xs_k);
  act_quant_e<<<dim3(Tt), dim3(256), 0, stream>>>(value, xq_v, xs_v);

  gemm_i8<<<dim3(Ee/64,  Tt/64), dim3(256), 0, stream>>>(xq_q, s_q, xs_q, stats, 0, Pq, Tt, Ee,  Ee);
  gemm_i8<<<dim3(KVd/64, Tt/64), dim3(256), 0, stream>>>(xq_k, s_k, xs_k, stats, 1, Pk, Tt, KVd, Ee);
  gemm_i8<<<dim3(KVd/64, Tt/64), dim3(256), 0, stream>>>(xq_v, s_v, xs_v, stats, 2, Pv, Tt, KVd, Ee);

  k_to_f16<<<dim3((Tt*KVd)/(256*8)), dim3(256), 0, stream>>>(Pk, Pkh);
  v_transpose<<<dim3(Nn/64, Bb*KVH), dim3(256), 0, stream>>>(Pv, Pvt);

  attn_mfma<<<dim3(Nn/16, KVH, Bb), dim3(64), 0, stream>>>(Pq, Pkh, Pvt, AO);

  ln_quant<<<dim3(Tt), dim3(128), 0, stream>>>(AO, ln_g, ln_b, oq, os_);

  gemm_i8<<<dim3(Ee/64, Tt/64), dim3(256), 0, stream>>>(oq, s_o, os_, stats, 3, out, Tt, Ee, KVd);
}

// Round 4
// 486.346 us; speedup vs baseline: 7.9516x; 2.0689x over previous
//
#include <hip/hip_runtime.h>
#include <stdint.h>
#include <stddef.h>

// ---------------- problem constants ----------------
constexpr int Bb  = 4;
constexpr int Nn  = 2048;
constexpr int Ee  = 1024;    // embed dim
constexpr int KVd = 512;     // kv dim
constexpr int HDd = 128;     // head dim
constexpr int KVH = 4;       // kv heads
constexpr int Tt  = Bb * Nn; // 8192 tokens

typedef _Float16 half8 __attribute__((ext_vector_type(8)));
typedef float    float4_t __attribute__((ext_vector_type(4)));
typedef int      i32x4 __attribute__((ext_vector_type(4)));

// ---------------- workspace layout (bytes) ----------------
constexpr size_t OFF_STATS = 0;                                  // 8 floats
constexpr size_t OFF_SQ  = 256;                                  // 1 MB  int8 sign(w_q-mean)
constexpr size_t OFF_SK  = OFF_SQ  + (size_t)Ee*Ee;              // 512 KB
constexpr size_t OFF_SV  = OFF_SK  + (size_t)KVd*Ee;             // 512 KB
constexpr size_t OFF_SO  = OFF_SV  + (size_t)KVd*Ee;             // 512 KB
constexpr size_t OFF_XQQ = OFF_SO  + (size_t)Ee*KVd;             // 8 MB  int8 quant inputs
constexpr size_t OFF_XQK = OFF_XQQ + (size_t)Tt*Ee;
constexpr size_t OFF_XQV = OFF_XQK + (size_t)Tt*Ee;
constexpr size_t OFF_XSQ = OFF_XQV + (size_t)Tt*Ee;              // per-token dequant scales
constexpr size_t OFF_XSK = OFF_XSQ + (size_t)Tt*4;
constexpr size_t OFF_XSV = OFF_XSK + (size_t)Tt*4;
constexpr size_t OFF_PQ  = OFF_XSV + (size_t)Tt*4;               // 32 MB fp32 q-proj
constexpr size_t OFF_PK  = OFF_PQ  + (size_t)Tt*Ee*4;            // 16 MB
constexpr size_t OFF_PV  = OFF_PK  + (size_t)Tt*KVd*4;           // 16 MB
// aliases (regions dead by the time these are written):
constexpr size_t OFF_PKH = OFF_XQQ;                              // 8 MB f16 K (xq_q dead after gemm Q)
constexpr size_t OFF_PVT = OFF_XQK;                              // 8 MB f16 V^T (xq_k dead after gemm KV)
constexpr size_t OFF_AO  = OFF_PK;                               // 16 MB over Pk fp32 (dead after k_to_f16)
constexpr size_t OFF_OQ  = OFF_XQV;                              // 4 MB over XQV (dead after gemm KV)
constexpr size_t OFF_OS  = OFF_OQ + (size_t)Tt*KVd;              // 32 KB, still inside XQV
constexpr size_t OFF_PART = OFF_PQ;                              // 4 KB partials alias Pq (consumed first)

// ---------------- DPP 16-lane replicated reductions (VALU-only) ----------------
template <int CTRL>
__device__ __forceinline__ float dpp_f(float x) {
  int i = __builtin_bit_cast(int, x);
  i = __builtin_amdgcn_update_dpp(0, i, CTRL, 0xF, 0xF, true);
  return __builtin_bit_cast(float, i);
}
__device__ __forceinline__ float red16_max(float x) {
  x = fmaxf(x, dpp_f<0xB1>(x));    // quad_perm [1,0,3,2]  (xor 1)
  x = fmaxf(x, dpp_f<0x4E>(x));    // quad_perm [2,3,0,1]  (xor 2)
  x = fmaxf(x, dpp_f<0x141>(x));   // row_half_mirror      (reduce across quads in 8)
  x = fmaxf(x, dpp_f<0x140>(x));   // row_mirror           (reduce across 8-halves)
  return x;
}
__device__ __forceinline__ float red16_sum(float x) {
  x += dpp_f<0xB1>(x);
  x += dpp_f<0x4E>(x);
  x += dpp_f<0x141>(x);
  x += dpp_f<0x140>(x);
  return x;
}

// ---------------- weight stats, stage 1 ----------------
constexpr int SB = 64;  // stat blocks per matrix

__global__ __launch_bounds__(256) void weight_stats_part(
    const float* __restrict__ w0, const float* __restrict__ w1,
    const float* __restrict__ w2, const float* __restrict__ w3,
    double* __restrict__ partials)
{
  const float* w; int n;
  switch (blockIdx.y) {
    case 0:  w = w0; n = Ee*Ee;  break;
    case 1:  w = w1; n = KVd*Ee; break;
    case 2:  w = w2; n = KVd*Ee; break;
    default: w = w3; n = Ee*KVd; break;
  }
  const int nv = n >> 2;
  double s = 0.0, sa = 0.0;
  for (int i = blockIdx.x * 256 + threadIdx.x; i < nv; i += SB * 256) {
    float4 v = ((const float4*)w)[i];
    s  += (double)v.x + (double)v.y + (double)v.z + (double)v.w;
    sa += (double)fabsf(v.x) + (double)fabsf(v.y) + (double)fabsf(v.z) + (double)fabsf(v.w);
  }
  __shared__ double r0[256], r1[256];
  r0[threadIdx.x] = s; r1[threadIdx.x] = sa;
  __syncthreads();
  for (int st = 128; st > 0; st >>= 1) {
    if (threadIdx.x < st) { r0[threadIdx.x] += r0[threadIdx.x+st]; r1[threadIdx.x] += r1[threadIdx.x+st]; }
    __syncthreads();
  }
  if (threadIdx.x == 0) {
    size_t o = ((size_t)blockIdx.y * SB + blockIdx.x) * 2;
    partials[o]   = r0[0];
    partials[o+1] = r1[0];
  }
}

__global__ __launch_bounds__(64) void weight_stats_fin(
    const double* __restrict__ partials, float* __restrict__ stats)
{
  int m = threadIdx.x;
  if (m < 4) {
    double s = 0.0, sa = 0.0;
    for (int i = 0; i < SB; i++) {
      s  += partials[((size_t)m * SB + i) * 2];
      sa += partials[((size_t)m * SB + i) * 2 + 1];
    }
    int n = (m == 0) ? Ee*Ee : (m == 3 ? Ee*KVd : KVd*Ee);
    stats[2*m]   = (float)(s  / n);
    stats[2*m+1] = (float)(sa / n);
  }
}

// ---------------- ternary weight signs ----------------
__global__ __launch_bounds__(256) void quant_w(
    const float* __restrict__ w, int8_t* __restrict__ s, int n,
    const float* __restrict__ stats, int idx)
{
  int i = blockIdx.x * 256 + threadIdx.x;
  if (i < n) {
    float d = w[i] - stats[2*idx];
    s[i] = (d > 0.f) ? (int8_t)1 : ((d < 0.f) ? (int8_t)-1 : (int8_t)0);
  }
}

// ---------------- fused rmsnorm + int8 act quant (dim=1024) ----------------
__global__ __launch_bounds__(256) void act_quant_e(
    const float* __restrict__ x, int8_t* __restrict__ q, float* __restrict__ dq)
{
  __shared__ float r0[256], r1[256];
  __shared__ float sb[2];
  const int t = blockIdx.x, tid = threadIdx.x;
  float4 a = ((const float4*)(x + (size_t)t * Ee))[tid];
  float ss = a.x*a.x + a.y*a.y + a.z*a.z + a.w*a.w;
  float mx = fmaxf(fmaxf(fabsf(a.x), fabsf(a.y)), fmaxf(fabsf(a.z), fabsf(a.w)));
  r0[tid] = ss; r1[tid] = mx;
  __syncthreads();
  for (int st = 128; st > 0; st >>= 1) {
    if (tid < st) { r0[tid] += r0[tid+st]; r1[tid] = fmaxf(r1[tid], r1[tid+st]); }
    __syncthreads();
  }
  if (tid == 0) {
    float nrm = sqrtf(r0[0]);
    float rn  = sqrtf((float)Ee) / fmaxf(nrm, 1e-12f);
    float sc  = 127.0f / fmaxf(r1[0] * rn, 1e-5f);
    sb[0] = rn; sb[1] = sc;
    dq[t] = 1.0f / sc;
  }
  __syncthreads();
  const float rn = sb[0], sc = sb[1];
  char4 o;
  o.x = (signed char)fmaxf(fminf(rintf((a.x*rn)*sc), 127.f), -128.f);
  o.y = (signed char)fmaxf(fminf(rintf((a.y*rn)*sc), 127.f), -128.f);
  o.z = (signed char)fmaxf(fminf(rintf((a.z*rn)*sc), 127.f), -128.f);
  o.w = (signed char)fmaxf(fminf(rintf((a.w*rn)*sc), 127.f), -128.f);
  ((char4*)(q + (size_t)t * Ee))[tid] = o;
}

// ---------------- int8 x ternary GEMM via MFMA (exact i32 accumulate) ----------------
// C[m,n] = xs[m] * wscale * sum_k A[m,k]*B[n,k];  tile 128x128, BK=64, 4 waves 2x2
__device__ __forceinline__ void gemm_core(
    const int8_t* __restrict__ A, const int8_t* __restrict__ Bm,
    const float* __restrict__ xs, const float* __restrict__ stats, int widx,
    float* __restrict__ C, int Nc, int K, int bx, int by)
{
  __shared__ int8_t As[128 * 80];   // 80-B padded rows: frag reads 2-way conflicts only
  __shared__ int8_t Bs[128 * 80];
  const int tid = threadIdx.x;
  const int row0 = by * 128, col0 = bx * 128;
  const int lane = tid & 63, wave = tid >> 6;
  const int wr = wave >> 1, wc = wave & 1;
  const int c = lane & 15, quad = lane >> 4;

  i32x4 acc[4][4];
  #pragma unroll
  for (int mt = 0; mt < 4; mt++)
    #pragma unroll
    for (int nt = 0; nt < 4; nt++) acc[mt][nt] = (i32x4){0, 0, 0, 0};

  const int srow = tid >> 2;         // 0..63
  const int schunk = (tid & 3) * 16; // byte offset of 16-B chunk

  for (int k0 = 0; k0 < K; k0 += 64) {
    int4 a0 = *(const int4*)(A  + (size_t)(row0 + srow)      * K + k0 + schunk);
    int4 a1 = *(const int4*)(A  + (size_t)(row0 + 64 + srow) * K + k0 + schunk);
    int4 b0 = *(const int4*)(Bm + (size_t)(col0 + srow)      * K + k0 + schunk);
    int4 b1 = *(const int4*)(Bm + (size_t)(col0 + 64 + srow) * K + k0 + schunk);
    __syncthreads();
    *(int4*)&As[srow * 80 + schunk]        = a0;
    *(int4*)&As[(64 + srow) * 80 + schunk] = a1;
    *(int4*)&Bs[srow * 80 + schunk]        = b0;
    *(int4*)&Bs[(64 + srow) * 80 + schunk] = b1;
    __syncthreads();
    i32x4 af[4], bf[4];
    #pragma unroll
    for (int mt = 0; mt < 4; mt++)
      af[mt] = *(const i32x4*)&As[(wr * 64 + mt * 16 + c) * 80 + quad * 16];
    #pragma unroll
    for (int nt = 0; nt < 4; nt++)
      bf[nt] = *(const i32x4*)&Bs[(wc * 64 + nt * 16 + c) * 80 + quad * 16];
    #pragma unroll
    for (int mt = 0; mt < 4; mt++)
      #pragma unroll
      for (int nt = 0; nt < 4; nt++)
        acc[mt][nt] = __builtin_amdgcn_mfma_i32_16x16x64_i8(af[mt], bf[nt], acc[mt][nt], 0, 0, 0);
  }
  const float wsc = stats[2 * widx + 1];
  #pragma unroll
  for (int mt = 0; mt < 4; mt++)
    #pragma unroll
    for (int j = 0; j < 4; j++) {
      int m = row0 + wr * 64 + mt * 16 + quad * 4 + j;
      float rowscale = xs[m] * wsc;
      #pragma unroll
      for (int nt = 0; nt < 4; nt++)
        C[(size_t)m * Nc + col0 + wc * 64 + nt * 16 + c] = (float)acc[mt][nt][j] * rowscale;
    }
}

__global__ __launch_bounds__(256) void gemm_one(
    const int8_t* __restrict__ A, const int8_t* __restrict__ Bm,
    const float* __restrict__ xs, const float* __restrict__ stats, int widx,
    float* __restrict__ C, int Nc, int K)
{
  gemm_core(A, Bm, xs, stats, widx, C, Nc, K, blockIdx.x, blockIdx.y);
}

__global__ __launch_bounds__(256) void gemm_kv(
    const int8_t* __restrict__ A0, const int8_t* __restrict__ B0,
    const float* __restrict__ xs0, float* __restrict__ C0,
    const int8_t* __restrict__ A1, const int8_t* __restrict__ B1,
    const float* __restrict__ xs1, float* __restrict__ C1,
    const float* __restrict__ stats)
{
  if (blockIdx.z == 0)
    gemm_core(A0, B0, xs0, stats, 1, C0, KVd, Ee, blockIdx.x, blockIdx.y);
  else
    gemm_core(A1, B1, xs1, stats, 2, C1, KVd, Ee, blockIdx.x, blockIdx.y);
}

// ---------------- Pk fp32 -> f16 ----------------
__global__ __launch_bounds__(256) void k_to_f16(
    const float* __restrict__ pk, _Float16* __restrict__ pkh)
{
  size_t i = ((size_t)blockIdx.x * 256 + threadIdx.x) * 8;
  float4 a = *(const float4*)(pk + i);
  float4 b = *(const float4*)(pk + i + 4);
  half8 o;
  o[0]=(_Float16)a.x; o[1]=(_Float16)a.y; o[2]=(_Float16)a.z; o[3]=(_Float16)a.w;
  o[4]=(_Float16)b.x; o[5]=(_Float16)b.y; o[6]=(_Float16)b.z; o[7]=(_Float16)b.w;
  *(half8*)(pkh + i) = o;
}

// ---------------- Pv fp32 [tok][512] -> Pvt f16 [bh][d=128][s=2048] ----------------
__global__ __launch_bounds__(256) void v_transpose(
    const float* __restrict__ pv, _Float16* __restrict__ pvt)
{
  __shared__ _Float16 lt[128][72];
  const int st = blockIdx.x;          // s-tile (64 tokens)
  const int bh = blockIdx.y;          // b*4+h
  const int b = bh >> 2, h = bh & 3;
  const int t = threadIdx.x;
  const int dc = (t & 31) * 4, srow = t >> 5;
  #pragma unroll
  for (int p = 0; p < 8; p++) {
    int s = srow + 8 * p;
    float4 v = *(const float4*)(pv + (size_t)(b * Nn + st * 64 + s) * KVd + h * HDd + dc);
    lt[dc+0][s] = (_Float16)v.x; lt[dc+1][s] = (_Float16)v.y;
    lt[dc+2][s] = (_Float16)v.z; lt[dc+3][s] = (_Float16)v.w;
  }
  __syncthreads();
  const int d = t >> 1, sh = (t & 1) * 32;
  _Float16* op = pvt + ((size_t)bh * HDd + d) * Nn + st * 64 + sh;
  #pragma unroll
  for (int m = 0; m < 4; m++)
    *(half8*)(op + m * 8) = *(const half8*)&lt[d][sh + m * 8];
}

// ---------------- MFMA flash attention (DPP softmax + register prefetch) ----------------
__global__ __launch_bounds__(64) void attn_mfma(
    const float* __restrict__ Pq, const _Float16* __restrict__ Pkh,
    const _Float16* __restrict__ Pvt, float* __restrict__ AO)
{
  __shared__ _Float16 stile[16 * 72];   // wave-private P tile
  const int lane = threadIdx.x;
  const int c = lane & 15, quad = lane >> 4;
  const int qrow0 = blockIdx.x << 4;
  const int h = blockIdx.y, b = blockIdx.z;
  const int bh = b * KVH + h;
  const size_t tokbase = (size_t)b * Nn;

  // Q fragments in registers (combined group-sum, /128 folded)
  half8 qa[4];
  {
    const float* qp = Pq + (tokbase + qrow0 + c) * Ee + (2 * h) * HDd;
    #pragma unroll
    for (int kc = 0; kc < 4; kc++) {
      int k0 = kc * 32 + quad * 8;
      float4 u0 = *(const float4*)(qp + k0);
      float4 u1 = *(const float4*)(qp + k0 + 4);
      float4 w0 = *(const float4*)(qp + HDd + k0);
      float4 w1 = *(const float4*)(qp + HDd + k0 + 4);
      half8 q8;
      q8[0] = (_Float16)((u0.x + w0.x) * 0.0078125f);
      q8[1] = (_Float16)((u0.y + w0.y) * 0.0078125f);
      q8[2] = (_Float16)((u0.z + w0.z) * 0.0078125f);
      q8[3] = (_Float16)((u0.w + w0.w) * 0.0078125f);
      q8[4] = (_Float16)((u1.x + w1.x) * 0.0078125f);
      q8[5] = (_Float16)((u1.y + w1.y) * 0.0078125f);
      q8[6] = (_Float16)((u1.z + w1.z) * 0.0078125f);
      q8[7] = (_Float16)((u1.w + w1.w) * 0.0078125f);
      qa[kc] = q8;
    }
  }

  float4_t oa[8];
  #pragma unroll
  for (int g = 0; g < 8; g++) oa[g] = (float4_t){0.f, 0.f, 0.f, 0.f};
  float m_i[4] = {-1e30f, -1e30f, -1e30f, -1e30f};
  float l_i[4] = {0.f, 0.f, 0.f, 0.f};

  const _Float16* kbase = Pkh + tokbase * KVd + h * HDd;
  const _Float16* vbase = Pvt + (size_t)bh * HDd * Nn;

  // prologue: resident K/V fragments for tile 0
  half8 kb[4][4], vb[8][2];
  #pragma unroll
  for (int nb = 0; nb < 4; nb++) {
    const _Float16* kp = kbase + (size_t)(nb * 16 + c) * KVd;
    #pragma unroll
    for (int kc = 0; kc < 4; kc++) kb[nb][kc] = *(const half8*)(kp + kc * 32 + quad * 8);
  }
  #pragma unroll
  for (int g = 0; g < 8; g++) {
    const _Float16* vp = vbase + (size_t)(g * 16 + c) * Nn;
    vb[g][0] = *(const half8*)(vp + quad * 8);
    vb[g][1] = *(const half8*)(vp + 32 + quad * 8);
  }

  for (int kt = 0; kt < Nn / 64; kt++) {
    const int ktn = (kt < Nn / 64 - 1) ? kt + 1 : kt;
    const int s0n = ktn * 64;
    // ---- S = Q K^T from resident kb ----
    float4_t sfr[4];
    #pragma unroll
    for (int nb = 0; nb < 4; nb++) {
      float4_t acc = (float4_t){0.f, 0.f, 0.f, 0.f};
      #pragma unroll
      for (int kc = 0; kc < 4; kc++)
        acc = __builtin_amdgcn_mfma_f32_16x16x32_f16(qa[kc], kb[nb][kc], acc, 0, 0, 0);
      sfr[nb] = acc;
    }
    // ---- prefetch next K tile (latency hidden by softmax+LDS+PV) ----
    #pragma unroll
    for (int nb = 0; nb < 4; nb++) {
      const _Float16* kp = kbase + (size_t)(s0n + nb * 16 + c) * KVd;
      #pragma unroll
      for (int kc = 0; kc < 4; kc++) kb[nb][kc] = *(const half8*)(kp + kc * 32 + quad * 8);
    }
    // ---- online softmax, DPP reductions (VALU only) ----
    float alpha[4];
    #pragma unroll
    for (int j = 0; j < 4; j++) {
      float t = fmaxf(fmaxf(sfr[0][j], sfr[1][j]), fmaxf(sfr[2][j], sfr[3][j]));
      t = red16_max(t);
      float mnew = fmaxf(m_i[j], t);
      alpha[j] = __expf(m_i[j] - mnew);
      m_i[j] = mnew;
    }
    float p[4][4];
    float rs[4] = {0.f, 0.f, 0.f, 0.f};
    #pragma unroll
    for (int nb = 0; nb < 4; nb++)
      #pragma unroll
      for (int j = 0; j < 4; j++) {
        p[nb][j] = __expf(sfr[nb][j] - m_i[j]);
        rs[j] += p[nb][j];
      }
    #pragma unroll
    for (int j = 0; j < 4; j++) l_i[j] = l_i[j] * alpha[j] + red16_sum(rs[j]);
    // ---- P: C-layout -> LDS -> A-layout ----
    __syncthreads();
    #pragma unroll
    for (int nb = 0; nb < 4; nb++)
      #pragma unroll
      for (int j = 0; j < 4; j++)
        stile[(quad * 4 + j) * 72 + nb * 16 + c] = (_Float16)p[nb][j];
    __syncthreads();
    half8 pa0 = *(const half8*)&stile[c * 72 + quad * 8];
    half8 pa1 = *(const half8*)&stile[c * 72 + 32 + quad * 8];
    // ---- O rescale + PV from resident vb ----
    #pragma unroll
    for (int g = 0; g < 8; g++) {
      oa[g][0] *= alpha[0]; oa[g][1] *= alpha[1];
      oa[g][2] *= alpha[2]; oa[g][3] *= alpha[3];
    }
    #pragma unroll
    for (int g = 0; g < 8; g++) {
      oa[g] = __builtin_amdgcn_mfma_f32_16x16x32_f16(pa0, vb[g][0], oa[g], 0, 0, 0);
      oa[g] = __builtin_amdgcn_mfma_f32_16x16x32_f16(pa1, vb[g][1], oa[g], 0, 0, 0);
    }
    // ---- prefetch next V tile ----
    #pragma unroll
    for (int g = 0; g < 8; g++) {
      const _Float16* vp = vbase + (size_t)(g * 16 + c) * Nn + s0n;
      vb[g][0] = *(const half8*)(vp + quad * 8);
      vb[g][1] = *(const half8*)(vp + 32 + quad * 8);
    }
  }
  // ---- epilogue ----
  float invl[4];
  #pragma unroll
  for (int j = 0; j < 4; j++) invl[j] = 1.0f / l_i[j];
  #pragma unroll
  for (int g = 0; g < 8; g++)
    #pragma unroll
    for (int j = 0; j < 4; j++)
      AO[(tokbase + qrow0 + quad * 4 + j) * KVd + h * HDd + g * 16 + c] = oa[g][j] * invl[j];
}

// ---------------- fused LayerNorm + rmsnorm + int8 quant (dim=512) ----------------
__global__ __launch_bounds__(128) void ln_quant(
    const float* __restrict__ AO, const float* __restrict__ g, const float* __restrict__ be,
    int8_t* __restrict__ oq, float* __restrict__ dq)
{
  __shared__ float r0[128], r1[128];
  __shared__ float sb[2];
  const int t = blockIdx.x, tid = threadIdx.x;
  float4 a = ((const float4*)(AO + (size_t)t * KVd))[tid];
  float s  = a.x + a.y + a.z + a.w;
  float ss = a.x*a.x + a.y*a.y + a.z*a.z + a.w*a.w;
  r0[tid] = s; r1[tid] = ss;
  __syncthreads();
  for (int st = 64; st > 0; st >>= 1) {
    if (tid < st) { r0[tid] += r0[tid+st]; r1[tid] += r1[tid+st]; }
    __syncthreads();
  }
  if (tid == 0) {
    float mu  = r0[0] / (float)KVd;
    float var = r1[0] / (float)KVd - mu*mu;
    sb[0] = mu;
    sb[1] = 1.0f / sqrtf(var + 1e-5f);
  }
  __syncthreads();
  const float mu = sb[0], iv = sb[1];
  float4 gv = ((const float4*)g)[tid];
  float4 bv = ((const float4*)be)[tid];
  float4 y;
  y.x = (a.x - mu) * iv * gv.x + bv.x;
  y.y = (a.y - mu) * iv * gv.y + bv.y;
  y.z = (a.z - mu) * iv * gv.z + bv.z;
  y.w = (a.w - mu) * iv * gv.w + bv.w;
  float ss2 = y.x*y.x + y.y*y.y + y.z*y.z + y.w*y.w;
  float mx  = fmaxf(fmaxf(fabsf(y.x), fabsf(y.y)), fmaxf(fabsf(y.z), fabsf(y.w)));
  __syncthreads();
  r0[tid] = ss2; r1[tid] = mx;
  __syncthreads();
  for (int st = 64; st > 0; st >>= 1) {
    if (tid < st) { r0[tid] += r0[tid+st]; r1[tid] = fmaxf(r1[tid], r1[tid+st]); }
    __syncthreads();
  }
  if (tid == 0) {
    float nrm = sqrtf(r0[0]);
    float rn  = sqrtf((float)KVd) / fmaxf(nrm, 1e-12f);
    float sc  = 127.0f / fmaxf(r1[0] * rn, 1e-5f);
    sb[0] = rn; sb[1] = sc;
    dq[t] = 1.0f / sc;
  }
  __syncthreads();
  const float rn = sb[0], sc = sb[1];
  char4 o;
  o.x = (signed char)fmaxf(fminf(rintf((y.x*rn)*sc), 127.f), -128.f);
  o.y = (signed char)fmaxf(fminf(rintf((y.y*rn)*sc), 127.f), -128.f);
  o.z = (signed char)fmaxf(fminf(rintf((y.z*rn)*sc), 127.f), -128.f);
  o.w = (signed char)fmaxf(fminf(rintf((y.w*rn)*sc), 127.f), -128.f);
  ((char4*)(oq + (size_t)t * KVd))[tid] = o;
}

// ---------------- launch ----------------
extern "C" void kernel_launch(void* const* d_in, const int* in_sizes, int n_in,
                              void* d_out, int out_size, void* d_ws, size_t ws_size,
                              hipStream_t stream)
{
  (void)in_sizes; (void)n_in; (void)out_size; (void)ws_size;
  const float* query = (const float*)d_in[0];
  const float* key_  = (const float*)d_in[1];
  const float* value = (const float*)d_in[2];
  const float* w_q   = (const float*)d_in[3];
  const float* w_k   = (const float*)d_in[4];
  const float* w_v   = (const float*)d_in[5];
  const float* w_o   = (const float*)d_in[6];
  const float* ln_g  = (const float*)d_in[7];
  const float* ln_b  = (const float*)d_in[8];
  float* out = (float*)d_out;

  char* ws = (char*)d_ws;
  float*     stats = (float*)    (ws + OFF_STATS);
  int8_t*    s_q   = (int8_t*)   (ws + OFF_SQ);
  int8_t*    s_k   = (int8_t*)   (ws + OFF_SK);
  int8_t*    s_v   = (int8_t*)   (ws + OFF_SV);
  int8_t*    s_o   = (int8_t*)   (ws + OFF_SO);
  int8_t*    xq_q  = (int8_t*)   (ws + OFF_XQQ);
  int8_t*    xq_k  = (int8_t*)   (ws + OFF_XQK);
  int8_t*    xq_v  = (int8_t*)   (ws + OFF_XQV);
  float*     xs_q  = (float*)    (ws + OFF_XSQ);
  float*     xs_k  = (float*)    (ws + OFF_XSK);
  float*     xs_v  = (float*)    (ws + OFF_XSV);
  float*     Pq    = (float*)    (ws + OFF_PQ);
  float*     Pk    = (float*)    (ws + OFF_PK);
  float*     Pv    = (float*)    (ws + OFF_PV);
  double*    part  = (double*)   (ws + OFF_PART);
  _Float16*  Pkh   = (_Float16*) (ws + OFF_PKH);
  _Float16*  Pvt   = (_Float16*) (ws + OFF_PVT);
  float*     AO    = (float*)    (ws + OFF_AO);
  int8_t*    oq    = (int8_t*)   (ws + OFF_OQ);
  float*     os_   = (float*)    (ws + OFF_OS);

  weight_stats_part<<<dim3(SB, 4), dim3(256), 0, stream>>>(w_q, w_k, w_v, w_o, part);
  weight_stats_fin<<<dim3(1), dim3(64), 0, stream>>>(part, stats);

  quant_w<<<dim3((Ee*Ee)/256),  dim3(256), 0, stream>>>(w_q, s_q, Ee*Ee,  stats, 0);
  quant_w<<<dim3((KVd*Ee)/256), dim3(256), 0, stream>>>(w_k, s_k, KVd*Ee, stats, 1);
  quant_w<<<dim3((KVd*Ee)/256), dim3(256), 0, stream>>>(w_v, s_v, KVd*Ee, stats, 2);
  quant_w<<<dim3((Ee*KVd)/256), dim3(256), 0, stream>>>(w_o, s_o, Ee*KVd, stats, 3);

  act_quant_e<<<dim3(Tt), dim3(256), 0, stream>>>(query, xq_q, xs_q);
  act_quant_e<<<dim3(Tt), dim3(256), 0, stream>>>(key_,  xq_k, xs_k);
  act_quant_e<<<dim3(Tt), dim3(256), 0, stream>>>(value, xq_v, xs_v);

  gemm_one<<<dim3(Ee/128, Tt/128), dim3(256), 0, stream>>>(xq_q, s_q, xs_q, stats, 0, Pq, Ee, Ee);
  gemm_kv<<<dim3(KVd/128, Tt/128, 2), dim3(256), 0, stream>>>(
      xq_k, s_k, xs_k, Pk, xq_v, s_v, xs_v, Pv, stats);

  k_to_f16<<<dim3((Tt*KVd)/(256*8)), dim3(256), 0, stream>>>(Pk, Pkh);
  v_transpose<<<dim3(Nn/64, Bb*KVH), dim3(256), 0, stream>>>(Pv, Pvt);

  attn_mfma<<<dim3(Nn/16, KVH, Bb), dim3(64), 0, stream>>>(Pq, Pkh, Pvt, AO);

  ln_quant<<<dim3(Tt), dim3(128), 0, stream>>>(AO, ln_g, ln_b, oq, os_);

  gemm_one<<<dim3(Ee/128, Tt/128), dim3(256), 0, stream>>>(oq, s_o, os_, stats, 3, out, Ee, KVd);
}